// Round 9
// baseline (256.006 us; speedup 1.0000x reference)
//
#include <hip/hip_runtime.h>
#include <stdint.h>

// Problem constants (fixed by the reference)
#define BQ   2
#define NQ   8192
#define D1Q  128
#define D2Q  256
#define OUTQ 128
#define CATQ 384   // D1+D2
#define KQ   16

// ---------------------------------------------------------------------------
// Kernel 1: prep = W transpose + xyz1 norms in one launch.
// ---------------------------------------------------------------------------
__global__ void prep_kernel(const float* __restrict__ W, float* __restrict__ Wt,
                            const float* __restrict__ xyz1,
                            float4* __restrict__ xyz1n) {
    int flat = blockIdx.x * 256 + threadIdx.x;
    if (flat < CATQ * OUTQ) {
        int k = flat >> 7;          // / OUTQ
        int o = flat & (OUTQ - 1);
        Wt[flat] = W[o * CATQ + k];
    }
    if (flat < BQ * NQ) {
        float x = xyz1[flat * 3 + 0];
        float y = xyz1[flat * 3 + 1];
        float z = xyz1[flat * 3 + 2];
        float n;
        {
            #pragma clang fp contract(off)
            float px = x * x, py = y * y, pz = z * z;
            n = (px + py) + pz;
        }
        xyz1n[flat] = make_float4(x, y, z, n);
    }
}

__device__ __forceinline__ void fma4(float4& acc, float a, const float4& w) {
    acc.x = fmaf(a, w.x, acc.x);
    acc.y = fmaf(a, w.y, acc.y);
    acc.z = fmaf(a, w.z, acc.z);
    acc.w = fmaf(a, w.w, acc.w);
}

// ---------------------------------------------------------------------------
// Kernel 2 (R9): cache-streaming register GEMM at FULL occupancy.
// Block = 256 threads -> 8 rows x 128 cols; thread = 1 row x 4 cols.
// Grid = 2048 (8 blocks/CU = 8 waves/SIMD; R8 post-mortem: 4 waves/SIMD left
// proj at 15% VALUBusy / 81us latency-bound). VGPR stays small (~48) so
// 8 waves/SIMD is legal. Per k4: 5 VMEM vs 16 FMA.
// Floor: FMA 10.2us, W-L2 per XCD ~49MB ~11us (overlapped) -> ~15us target.
// ---------------------------------------------------------------------------
__global__ __launch_bounds__(256) void proj_kernel(
        const float* __restrict__ points1, const float* __restrict__ points2,
        const float* __restrict__ Wt, const float* __restrict__ bias,
        float* __restrict__ P1Wb, float* __restrict__ P2W) {
    const int tid = threadIdx.x;
    const int row = blockIdx.x * 8 + (tid >> 5);
    const int o0  = (tid & 31) * 4;       // output col base

    float4 acc = make_float4(0.f, 0.f, 0.f, 0.f);

    // ---- pass A: K=128 from points1 -> P1Wb (+bias) ----
    {
        const float* a0 = points1 + (size_t)row * D1Q;
        #pragma unroll 4
        for (int k4 = 0; k4 < 32; ++k4) {
            const float* wbase = Wt + (size_t)(k4 * 4) * OUTQ + o0;
            float4 w0 = *(const float4*)(wbase + 0 * OUTQ);
            float4 w1 = *(const float4*)(wbase + 1 * OUTQ);
            float4 w2 = *(const float4*)(wbase + 2 * OUTQ);
            float4 w3 = *(const float4*)(wbase + 3 * OUTQ);
            float4 av = *(const float4*)(a0 + k4 * 4);
            fma4(acc, av.x, w0); fma4(acc, av.y, w1);
            fma4(acc, av.z, w2); fma4(acc, av.w, w3);
        }
        float4 bv = *(const float4*)(bias + o0);
        acc.x += bv.x; acc.y += bv.y; acc.z += bv.z; acc.w += bv.w;
        *(float4*)&P1Wb[(size_t)row * OUTQ + o0] = acc;
        acc = make_float4(0.f, 0.f, 0.f, 0.f);
    }

    // ---- pass B: K=256 from points2 -> P2W ----
    {
        const float* a0 = points2 + (size_t)row * D2Q;
        #pragma unroll 4
        for (int k4 = 0; k4 < 64; ++k4) {
            const float* wbase = Wt + (size_t)(D1Q + k4 * 4) * OUTQ + o0;
            float4 w0 = *(const float4*)(wbase + 0 * OUTQ);
            float4 w1 = *(const float4*)(wbase + 1 * OUTQ);
            float4 w2 = *(const float4*)(wbase + 2 * OUTQ);
            float4 w3 = *(const float4*)(wbase + 3 * OUTQ);
            float4 av = *(const float4*)(a0 + k4 * 4);
            fma4(acc, av.x, w0); fma4(acc, av.y, w1);
            fma4(acc, av.z, w2); fma4(acc, av.w, w3);
        }
        *(float4*)&P2W[(size_t)row * OUTQ + o0] = acc;
    }
}

// numpy-exact squared distance (same rounding as the reference BLAS path)
__device__ __forceinline__ float npy_d2(float4 pt, float qx, float qy, float qz,
                                        float s2) {
    #pragma clang fp contract(off)
    float d0  = pt.x * qx;                 // rounded product
    float dot = fmaf(pt.y, qy, d0);        // explicit FMA chain
    dot       = fmaf(pt.z, qz, dot);
    float tt  = s2 + pt.w;                 // rounded add
    return tt - 2.0f * dot;                // 2*dot exact; rounded sub
}

// full ascending bitonic sort of one uint64 per lane across the wave
__device__ __forceinline__ uint64_t sort64(uint64_t x, int lane) {
    #pragma unroll
    for (int k = 2; k <= 64; k <<= 1) {
        #pragma unroll
        for (int j = k >> 1; j > 0; j >>= 1) {
            uint64_t p = __shfl_xor((unsigned long long)x, j, 64);
            bool keep_min = (((lane & j) == 0) == ((lane & k) == 0));
            bool pless    = p < x;
            x = (pless == keep_min) ? p : x;   // ties: same value either way
        }
    }
    return x;
}

// ---------------------------------------------------------------------------
// Kernel 3 (unchanged from R8): fused 16-NN + weights + gather/combine.
// ---------------------------------------------------------------------------
__global__ __launch_bounds__(256) void fpn_kernel(
        const float4* __restrict__ xyz1n, const float* __restrict__ xyz2,
        const float* __restrict__ P1Wb, const float* __restrict__ P2W,
        float* __restrict__ out) {
    __shared__ __align__(16) float4 xyzt4[1024];   // 16 KB tile
    __shared__ uint64_t wbuf[16][128];             // 16 KB candidate spill

    const int tid   = threadIdx.x;
    const int lane  = tid & 63;
    const int w     = tid >> 6;
    const int qbase = blockIdx.x * 16 + w * 4;     // wave's 4 queries
    const int b     = (blockIdx.x * 16) >> 13;     // uniform per block

    float qx[4], qy[4], qz[4], s2[4];
    #pragma unroll
    for (int j = 0; j < 4; ++j) {
        const float* qp = xyz2 + (size_t)(qbase + j) * 3;
        qx[j] = qp[0]; qy[j] = qp[1]; qz[j] = qp[2];
        {
            #pragma clang fp contract(off)
            float px = qx[j] * qx[j], py = qy[j] * qy[j], pz = qz[j] * qz[j];
            s2[j] = (px + py) + pz;
        }
    }

    const float4* xb = xyz1n + (size_t)b * NQ;

    // ---------------- Phase 1: branchless 4-query lane-min scan ----------------
    float mn[4];
    #pragma unroll
    for (int j = 0; j < 4; ++j) mn[j] = __uint_as_float(0x7F800000u);

    for (int tile = 0; tile < 8; ++tile) {
        __syncthreads();
        {
            const float4* s4 = xb + tile * 1024;
            #pragma unroll
            for (int v = tid; v < 1024; v += 256) xyzt4[v] = s4[v];
        }
        __syncthreads();
        #pragma unroll 4
        for (int s = 0; s < 16; ++s) {
            float4 pt = xyzt4[s * 64 + lane];
            #pragma unroll
            for (int j = 0; j < 4; ++j)
                mn[j] = fminf(mn[j], npy_d2(pt, qx[j], qy[j], qz[j], s2[j]));
        }
    }

    // 4 float bitonic sorts of lane minima; that[j] = rank 15 (provably safe)
    float that[4];
    #pragma unroll
    for (int j = 0; j < 4; ++j) {
        float x = mn[j];
        #pragma unroll
        for (int k = 2; k <= 64; k <<= 1) {
            #pragma unroll
            for (int jj = k >> 1; jj > 0; jj >>= 1) {
                float px = __shfl_xor(x, jj, 64);
                bool keep_min = (((lane & jj) == 0) == ((lane & k) == 0));
                float mnv = fminf(x, px), mxv = fmaxf(x, px);
                x = keep_min ? mnv : mxv;
            }
        }
        that[j] = __shfl(x, 15, 64);
    }

    // ---------------- Phase 2: gated compaction ----------------
    uint32_t cnt[4] = {0u, 0u, 0u, 0u};
    for (int tt = 0; tt < 8; ++tt) {
        const int tile = 7 - tt;                   // tile 7 still resident
        if (tt > 0) {
            __syncthreads();
            const float4* s4 = xb + tile * 1024;
            #pragma unroll
            for (int v = tid; v < 1024; v += 256) xyzt4[v] = s4[v];
            __syncthreads();
        }
        const uint32_t base = (uint32_t)tile * 1024u;
        #pragma unroll 4
        for (int s = 0; s < 16; ++s) {
            float4 pt = xyzt4[s * 64 + lane];
            const uint32_t pidx = base + (uint32_t)(s * 64 + lane);
            #pragma unroll
            for (int j = 0; j < 4; ++j) {
                float d2 = npy_d2(pt, qx[j], qy[j], qz[j], s2[j]);
                bool  v  = (d2 <= that[j]);
                uint64_t mask = __ballot((int)v);
                if (mask != 0ull) {                // scalar gate, ~15% taken
                    if (v) {
                        uint32_t below = __builtin_amdgcn_mbcnt_hi(
                            (uint32_t)(mask >> 32),
                            __builtin_amdgcn_mbcnt_lo((uint32_t)mask, 0u));
                        uint32_t pos    = cnt[j] + below;
                        uint32_t bits   = __float_as_uint(d2);
                        uint32_t mapped = bits ^ (0x80000000u |
                                          (uint32_t)((int32_t)bits >> 31));
                        if (pos < 128u)
                            wbuf[w * 4 + j][pos] =
                                ((uint64_t)mapped << 32) | (uint64_t)pidx;
                    }
                    cnt[j] += (uint32_t)__popcll(mask);
                }
            }
        }
    }

    // ---------------- per-query selection + weights + gather ----------------
    const float* p2b = P2W + (size_t)b * NQ * OUTQ;
    #pragma unroll
    for (int j = 0; j < 4; ++j) {
        const int qi = w * 4 + j;
        const uint32_t c = cnt[j];
        uint64_t mykey;
        if (c <= 64u) {                            // normal path
            uint64_t k0 = (lane < (int)c) ? wbuf[qi][lane] : ~0ull;
            mykey = sort64(k0, lane);
        } else {                                   // uniform fallback
            uint32_t cc = c > 128u ? 128u : c;
            uint64_t k0 = wbuf[qi][lane];
            uint64_t k1 = (lane + 64 < (int)cc) ? wbuf[qi][lane + 64] : ~0ull;
            k0 = sort64(k0, lane);
            k1 = sort64(k1, lane);
            uint64_t t1 = __shfl((unsigned long long)k1, lane & 15, 64);
            uint64_t km = (lane < 16) ? k0 : ((lane < 32) ? t1 : ~0ull);
            mykey = sort64(km, lane);
        }

        // inverse-distance weights (lanes 0..15 hold the 16 NN)
        uint32_t mhi   = (uint32_t)(mykey >> 32);
        uint32_t rbits = (mhi & 0x80000000u) ? (mhi ^ 0x80000000u) : ~mhi;
        float    d2w   = __uint_as_float(rbits);
        int      myidx = (int)(uint32_t)(mykey & 0xFFFFFFFFull);
        float recip = (lane < KQ) ? (1.0f / (d2w + 1e-8f)) : 0.0f;
        float tot = recip;
        #pragma unroll
        for (int sh = 1; sh < 16; sh <<= 1) tot += __shfl_xor(tot, sh, 64);
        float wgt = recip / tot;                   // valid in lanes 0..15

        // gather + combine: out = P1Wb[q] + sum_k w_k * P2W[idx_k]
        const float2* prow = (const float2*)(P1Wb + (size_t)(qbase + j) * OUTQ);
        float2 acc = prow[lane];
        #pragma unroll
        for (int k = 0; k < KQ; ++k) {
            int   kk = __builtin_amdgcn_readlane(myidx, k);
            float wk = __uint_as_float((uint32_t)__builtin_amdgcn_readlane(
                           (int)__float_as_uint(wgt), k));
            const float2 row = *(const float2*)(p2b + (size_t)kk * OUTQ + lane * 2);
            acc.x = fmaf(wk, row.x, acc.x);
            acc.y = fmaf(wk, row.y, acc.y);
        }
        *(float2*)(out + (size_t)(qbase + j) * OUTQ + lane * 2) = acc;
    }
}

// ---------------------------------------------------------------------------
// Launch
// ---------------------------------------------------------------------------
extern "C" void kernel_launch(void* const* d_in, const int* in_sizes, int n_in,
                              void* d_out, int out_size, void* d_ws, size_t ws_size,
                              hipStream_t stream) {
    const float* xyz1    = (const float*)d_in[0];
    const float* xyz2    = (const float*)d_in[1];
    const float* points1 = (const float*)d_in[2];
    const float* points2 = (const float*)d_in[3];
    const float* W       = (const float*)d_in[4];
    const float* bias    = (const float*)d_in[5];

    float* wsf  = (float*)d_ws;
    float* Wt   = wsf;                         // 384*128   = 49152 floats
    float* P1Wb = wsf + 49152;                 // 16384*128 = 2097152 floats
    float* P2W  = P1Wb + 2097152;              // 16384*128
    float4* xyz1n = (float4*)(P2W + 2097152);  // 16384 float4

    prep_kernel<<<192, 256, 0, stream>>>(W, Wt, xyz1, xyz1n);
    proj_kernel<<<(BQ * NQ) / 8, 256, 0, stream>>>(points1, points2, Wt, bias, P1Wb, P2W);
    fpn_kernel<<<(BQ * NQ) / 16, 256, 0, stream>>>(xyz1n, xyz2, P1Wb, P2W, (float*)d_out);
}

// Round 10
// 186.262 us; speedup vs baseline: 1.3744x; 1.3744x over previous
//
#include <hip/hip_runtime.h>
#include <stdint.h>

// Problem constants (fixed by the reference)
#define BQ   2
#define NQ   8192
#define D1Q  128
#define D2Q  256
#define OUTQ 128
#define CATQ 384   // D1+D2
#define KQ   16

// ---------------------------------------------------------------------------
// Kernel 1: prep = W transpose + xyz1 norms in one launch.
// ---------------------------------------------------------------------------
__global__ void prep_kernel(const float* __restrict__ W, float* __restrict__ Wt,
                            const float* __restrict__ xyz1,
                            float4* __restrict__ xyz1n) {
    int flat = blockIdx.x * 256 + threadIdx.x;
    if (flat < CATQ * OUTQ) {
        int k = flat >> 7;          // / OUTQ
        int o = flat & (OUTQ - 1);
        Wt[flat] = W[o * CATQ + k];
    }
    if (flat < BQ * NQ) {
        float x = xyz1[flat * 3 + 0];
        float y = xyz1[flat * 3 + 1];
        float z = xyz1[flat * 3 + 2];
        float n;
        {
            #pragma clang fp contract(off)
            float px = x * x, py = y * y, pz = z * z;
            n = (px + py) + pz;
        }
        xyz1n[flat] = make_float4(x, y, z, n);
    }
}

__device__ __forceinline__ void fma4(float4& acc, float a, const float4& w) {
    acc.x = fmaf(a, w.x, acc.x);
    acc.y = fmaf(a, w.y, acc.y);
    acc.z = fmaf(a, w.z, acc.z);
    acc.w = fmaf(a, w.w, acc.w);
}

// ---------------------------------------------------------------------------
// Kernel 2 (R10): LDS-staged-W GEMM.
// R9 post-mortem: per-wave full-Wt streaming = Wt_size x #waves of L2 reads
// (1.6 GB) with same-line camping -> 124us at 11% VALU. Fix structurally:
// stage each 32-krow Wt chunk (16 KB) ONCE per block in LDS, read via
// conflict-free ds_read_b128 (lanes 0-31 span 512 B, upper half broadcast).
// Block = 16 rows x 128 cols, thread = 2 rows x 4 cols. Grid 1024 =
// 4 blocks/CU = 4 waves/SIMD. Chunk order rotated per block to decorrelate
// the staging reads across blocks (fp chunk-reorder error ~1e-5, safe).
// W L2 traffic: 1024 x 196 KB = 200 MB (~6us). Pipes/CU: FMA 10us,
// DS ~25us -> DS-bound ~25-35us.
// ---------------------------------------------------------------------------
__global__ __launch_bounds__(256) void proj_kernel(
        const float* __restrict__ points1, const float* __restrict__ points2,
        const float* __restrict__ Wt, const float* __restrict__ bias,
        float* __restrict__ P1Wb, float* __restrict__ P2W) {
    __shared__ __align__(16) float Wl[32 * OUTQ];   // 16 KB W chunk

    const int tid  = threadIdx.x;
    const int bid  = blockIdx.x;
    const int rg   = tid >> 5;            // 0..7 -> rows rg*2, rg*2+1
    const int o0   = (tid & 31) * 4;      // output col base
    const int r0   = bid * 16 + rg * 2;

    float4 acc0 = make_float4(0.f, 0.f, 0.f, 0.f);
    float4 acc1 = make_float4(0.f, 0.f, 0.f, 0.f);

    // ---- pass A: K=128 (4 chunks of 32) from points1 -> P1Wb (+bias) ----
    for (int cc = 0; cc < 4; ++cc) {
        const int k0 = ((cc + bid) & 3) * 32;
        __syncthreads();                   // protect previous chunk's readers
        {
            const float4* src = (const float4*)(Wt + (size_t)k0 * OUTQ);
            float4* dst = (float4*)Wl;
            #pragma unroll
            for (int v = tid; v < 1024; v += 256) dst[v] = src[v];
        }
        __syncthreads();

        const float* a0 = points1 + (size_t)(r0 + 0) * D1Q + k0;
        const float* a1 = points1 + (size_t)(r0 + 1) * D1Q + k0;
        #pragma unroll
        for (int kk = 0; kk < 8; ++kk) {
            float4 av0 = *(const float4*)(a0 + kk * 4);
            float4 av1 = *(const float4*)(a1 + kk * 4);
            const float* wb = Wl + (kk * 4) * OUTQ + o0;
            float4 w0 = *(const float4*)(wb + 0 * OUTQ);
            float4 w1 = *(const float4*)(wb + 1 * OUTQ);
            float4 w2 = *(const float4*)(wb + 2 * OUTQ);
            float4 w3 = *(const float4*)(wb + 3 * OUTQ);
            fma4(acc0, av0.x, w0); fma4(acc0, av0.y, w1);
            fma4(acc0, av0.z, w2); fma4(acc0, av0.w, w3);
            fma4(acc1, av1.x, w0); fma4(acc1, av1.y, w1);
            fma4(acc1, av1.z, w2); fma4(acc1, av1.w, w3);
        }
    }
    {
        float4 bv = *(const float4*)(bias + o0);
        acc0.x += bv.x; acc0.y += bv.y; acc0.z += bv.z; acc0.w += bv.w;
        acc1.x += bv.x; acc1.y += bv.y; acc1.z += bv.z; acc1.w += bv.w;
        *(float4*)&P1Wb[(size_t)(r0 + 0) * OUTQ + o0] = acc0;
        *(float4*)&P1Wb[(size_t)(r0 + 1) * OUTQ + o0] = acc1;
        acc0 = make_float4(0.f, 0.f, 0.f, 0.f);
        acc1 = make_float4(0.f, 0.f, 0.f, 0.f);
    }

    // ---- pass B: K=256 (8 chunks of 32) from points2 -> P2W ----
    for (int cc = 0; cc < 8; ++cc) {
        const int ck = (cc + bid) & 7;
        const int k0 = ck * 32;            // offset within points2 row
        __syncthreads();
        {
            const float4* src = (const float4*)(Wt + (size_t)(D1Q + k0) * OUTQ);
            float4* dst = (float4*)Wl;
            #pragma unroll
            for (int v = tid; v < 1024; v += 256) dst[v] = src[v];
        }
        __syncthreads();

        const float* a0 = points2 + (size_t)(r0 + 0) * D2Q + k0;
        const float* a1 = points2 + (size_t)(r0 + 1) * D2Q + k0;
        #pragma unroll
        for (int kk = 0; kk < 8; ++kk) {
            float4 av0 = *(const float4*)(a0 + kk * 4);
            float4 av1 = *(const float4*)(a1 + kk * 4);
            const float* wb = Wl + (kk * 4) * OUTQ + o0;
            float4 w0 = *(const float4*)(wb + 0 * OUTQ);
            float4 w1 = *(const float4*)(wb + 1 * OUTQ);
            float4 w2 = *(const float4*)(wb + 2 * OUTQ);
            float4 w3 = *(const float4*)(wb + 3 * OUTQ);
            fma4(acc0, av0.x, w0); fma4(acc0, av0.y, w1);
            fma4(acc0, av0.z, w2); fma4(acc0, av0.w, w3);
            fma4(acc1, av1.x, w0); fma4(acc1, av1.y, w1);
            fma4(acc1, av1.z, w2); fma4(acc1, av1.w, w3);
        }
    }
    *(float4*)&P2W[(size_t)(r0 + 0) * OUTQ + o0] = acc0;
    *(float4*)&P2W[(size_t)(r0 + 1) * OUTQ + o0] = acc1;
}

// numpy-exact squared distance (same rounding as the reference BLAS path)
__device__ __forceinline__ float npy_d2(float4 pt, float qx, float qy, float qz,
                                        float s2) {
    #pragma clang fp contract(off)
    float d0  = pt.x * qx;                 // rounded product
    float dot = fmaf(pt.y, qy, d0);        // explicit FMA chain
    dot       = fmaf(pt.z, qz, dot);
    float tt  = s2 + pt.w;                 // rounded add
    return tt - 2.0f * dot;                // 2*dot exact; rounded sub
}

// full ascending bitonic sort of one uint64 per lane across the wave
__device__ __forceinline__ uint64_t sort64(uint64_t x, int lane) {
    #pragma unroll
    for (int k = 2; k <= 64; k <<= 1) {
        #pragma unroll
        for (int j = k >> 1; j > 0; j >>= 1) {
            uint64_t p = __shfl_xor((unsigned long long)x, j, 64);
            bool keep_min = (((lane & j) == 0) == ((lane & k) == 0));
            bool pless    = p < x;
            x = (pless == keep_min) ? p : x;   // ties: same value either way
        }
    }
    return x;
}

// ---------------------------------------------------------------------------
// Kernel 3 (unchanged from R8): fused 16-NN + weights + gather/combine.
// ---------------------------------------------------------------------------
__global__ __launch_bounds__(256) void fpn_kernel(
        const float4* __restrict__ xyz1n, const float* __restrict__ xyz2,
        const float* __restrict__ P1Wb, const float* __restrict__ P2W,
        float* __restrict__ out) {
    __shared__ __align__(16) float4 xyzt4[1024];   // 16 KB tile
    __shared__ uint64_t wbuf[16][128];             // 16 KB candidate spill

    const int tid   = threadIdx.x;
    const int lane  = tid & 63;
    const int w     = tid >> 6;
    const int qbase = blockIdx.x * 16 + w * 4;     // wave's 4 queries
    const int b     = (blockIdx.x * 16) >> 13;     // uniform per block

    float qx[4], qy[4], qz[4], s2[4];
    #pragma unroll
    for (int j = 0; j < 4; ++j) {
        const float* qp = xyz2 + (size_t)(qbase + j) * 3;
        qx[j] = qp[0]; qy[j] = qp[1]; qz[j] = qp[2];
        {
            #pragma clang fp contract(off)
            float px = qx[j] * qx[j], py = qy[j] * qy[j], pz = qz[j] * qz[j];
            s2[j] = (px + py) + pz;
        }
    }

    const float4* xb = xyz1n + (size_t)b * NQ;

    // ---------------- Phase 1: branchless 4-query lane-min scan ----------------
    float mn[4];
    #pragma unroll
    for (int j = 0; j < 4; ++j) mn[j] = __uint_as_float(0x7F800000u);

    for (int tile = 0; tile < 8; ++tile) {
        __syncthreads();
        {
            const float4* s4 = xb + tile * 1024;
            #pragma unroll
            for (int v = tid; v < 1024; v += 256) xyzt4[v] = s4[v];
        }
        __syncthreads();
        #pragma unroll 4
        for (int s = 0; s < 16; ++s) {
            float4 pt = xyzt4[s * 64 + lane];
            #pragma unroll
            for (int j = 0; j < 4; ++j)
                mn[j] = fminf(mn[j], npy_d2(pt, qx[j], qy[j], qz[j], s2[j]));
        }
    }

    // 4 float bitonic sorts of lane minima; that[j] = rank 15 (provably safe)
    float that[4];
    #pragma unroll
    for (int j = 0; j < 4; ++j) {
        float x = mn[j];
        #pragma unroll
        for (int k = 2; k <= 64; k <<= 1) {
            #pragma unroll
            for (int jj = k >> 1; jj > 0; jj >>= 1) {
                float px = __shfl_xor(x, jj, 64);
                bool keep_min = (((lane & jj) == 0) == ((lane & k) == 0));
                float mnv = fminf(x, px), mxv = fmaxf(x, px);
                x = keep_min ? mnv : mxv;
            }
        }
        that[j] = __shfl(x, 15, 64);
    }

    // ---------------- Phase 2: gated compaction ----------------
    uint32_t cnt[4] = {0u, 0u, 0u, 0u};
    for (int tt = 0; tt < 8; ++tt) {
        const int tile = 7 - tt;                   // tile 7 still resident
        if (tt > 0) {
            __syncthreads();
            const float4* s4 = xb + tile * 1024;
            #pragma unroll
            for (int v = tid; v < 1024; v += 256) xyzt4[v] = s4[v];
            __syncthreads();
        }
        const uint32_t base = (uint32_t)tile * 1024u;
        #pragma unroll 4
        for (int s = 0; s < 16; ++s) {
            float4 pt = xyzt4[s * 64 + lane];
            const uint32_t pidx = base + (uint32_t)(s * 64 + lane);
            #pragma unroll
            for (int j = 0; j < 4; ++j) {
                float d2 = npy_d2(pt, qx[j], qy[j], qz[j], s2[j]);
                bool  v  = (d2 <= that[j]);
                uint64_t mask = __ballot((int)v);
                if (mask != 0ull) {                // scalar gate, ~15% taken
                    if (v) {
                        uint32_t below = __builtin_amdgcn_mbcnt_hi(
                            (uint32_t)(mask >> 32),
                            __builtin_amdgcn_mbcnt_lo((uint32_t)mask, 0u));
                        uint32_t pos    = cnt[j] + below;
                        uint32_t bits   = __float_as_uint(d2);
                        uint32_t mapped = bits ^ (0x80000000u |
                                          (uint32_t)((int32_t)bits >> 31));
                        if (pos < 128u)
                            wbuf[w * 4 + j][pos] =
                                ((uint64_t)mapped << 32) | (uint64_t)pidx;
                    }
                    cnt[j] += (uint32_t)__popcll(mask);
                }
            }
        }
    }

    // ---------------- per-query selection + weights + gather ----------------
    const float* p2b = P2W + (size_t)b * NQ * OUTQ;
    #pragma unroll
    for (int j = 0; j < 4; ++j) {
        const int qi = w * 4 + j;
        const uint32_t c = cnt[j];
        uint64_t mykey;
        if (c <= 64u) {                            // normal path
            uint64_t k0 = (lane < (int)c) ? wbuf[qi][lane] : ~0ull;
            mykey = sort64(k0, lane);
        } else {                                   // uniform fallback
            uint32_t cc = c > 128u ? 128u : c;
            uint64_t k0 = wbuf[qi][lane];
            uint64_t k1 = (lane + 64 < (int)cc) ? wbuf[qi][lane + 64] : ~0ull;
            k0 = sort64(k0, lane);
            k1 = sort64(k1, lane);
            uint64_t t1 = __shfl((unsigned long long)k1, lane & 15, 64);
            uint64_t km = (lane < 16) ? k0 : ((lane < 32) ? t1 : ~0ull);
            mykey = sort64(km, lane);
        }

        // inverse-distance weights (lanes 0..15 hold the 16 NN)
        uint32_t mhi   = (uint32_t)(mykey >> 32);
        uint32_t rbits = (mhi & 0x80000000u) ? (mhi ^ 0x80000000u) : ~mhi;
        float    d2w   = __uint_as_float(rbits);
        int      myidx = (int)(uint32_t)(mykey & 0xFFFFFFFFull);
        float recip = (lane < KQ) ? (1.0f / (d2w + 1e-8f)) : 0.0f;
        float tot = recip;
        #pragma unroll
        for (int sh = 1; sh < 16; sh <<= 1) tot += __shfl_xor(tot, sh, 64);
        float wgt = recip / tot;                   // valid in lanes 0..15

        // gather + combine: out = P1Wb[q] + sum_k w_k * P2W[idx_k]
        const float2* prow = (const float2*)(P1Wb + (size_t)(qbase + j) * OUTQ);
        float2 acc = prow[lane];
        #pragma unroll
        for (int k = 0; k < KQ; ++k) {
            int   kk = __builtin_amdgcn_readlane(myidx, k);
            float wk = __uint_as_float((uint32_t)__builtin_amdgcn_readlane(
                           (int)__float_as_uint(wgt), k));
            const float2 row = *(const float2*)(p2b + (size_t)kk * OUTQ + lane * 2);
            acc.x = fmaf(wk, row.x, acc.x);
            acc.y = fmaf(wk, row.y, acc.y);
        }
        *(float2*)(out + (size_t)(qbase + j) * OUTQ + lane * 2) = acc;
    }
}

// ---------------------------------------------------------------------------
// Launch
// ---------------------------------------------------------------------------
extern "C" void kernel_launch(void* const* d_in, const int* in_sizes, int n_in,
                              void* d_out, int out_size, void* d_ws, size_t ws_size,
                              hipStream_t stream) {
    const float* xyz1    = (const float*)d_in[0];
    const float* xyz2    = (const float*)d_in[1];
    const float* points1 = (const float*)d_in[2];
    const float* points2 = (const float*)d_in[3];
    const float* W       = (const float*)d_in[4];
    const float* bias    = (const float*)d_in[5];

    float* wsf  = (float*)d_ws;
    float* Wt   = wsf;                         // 384*128   = 49152 floats
    float* P1Wb = wsf + 49152;                 // 16384*128 = 2097152 floats
    float* P2W  = P1Wb + 2097152;              // 16384*128
    float4* xyz1n = (float4*)(P2W + 2097152);  // 16384 float4

    prep_kernel<<<192, 256, 0, stream>>>(W, Wt, xyz1, xyz1n);
    proj_kernel<<<(BQ * NQ) / 16, 256, 0, stream>>>(points1, points2, Wt, bias, P1Wb, P2W);
    fpn_kernel<<<(BQ * NQ) / 16, 256, 0, stream>>>(xyz1n, xyz2, P1Wb, P2W, (float*)d_out);
}